// Round 1
// baseline (735.436 us; speedup 1.0000x reference)
//
#include <hip/hip_runtime.h>

#define N_NODES 262144
#define BGRAPHS 1024
#define NPG 256
#define LATENT 256
#define HIDDEN 512

typedef __attribute__((ext_vector_type(4))) float  f32x4;
typedef __attribute__((ext_vector_type(8))) short  short8;
typedef __attribute__((ext_vector_type(4))) int    int4v;
typedef __attribute__((ext_vector_type(2))) unsigned int uint2v;
typedef __attribute__((ext_vector_type(4))) float  float4v;

__device__ __forceinline__ unsigned short f2bf(float f) {
  union { float f; unsigned int u; } v; v.f = f;
  unsigned int u = v.u;
  unsigned int r = (u + 0x7fffu + ((u >> 16) & 1u)) >> 16;
  return (unsigned short)r;
}
__device__ __forceinline__ float silu_f(float x) { return x / (1.0f + __expf(-x)); }

// ---------------------------------------------------------------------------
// Weight prep: W0 [256,512] -> W0T bf16 [512][256]; W1 [512,512] -> W1T [512][512]
// ---------------------------------------------------------------------------
__global__ void prep_weights(const float* __restrict__ W0, const float* __restrict__ W1,
                             unsigned short* __restrict__ W0T, unsigned short* __restrict__ W1T) {
  int idx = blockIdx.x * blockDim.x + threadIdx.x;
  if (idx < HIDDEN * LATENT) {
    int n = idx / LATENT, k = idx - n * LATENT;
    W0T[idx] = f2bf(W0[k * HIDDEN + n]);
  } else {
    int idx2 = idx - HIDDEN * LATENT;
    if (idx2 < HIDDEN * HIDDEN) {
      int n = idx2 / HIDDEN, k = idx2 - n * HIDDEN;
      W1T[idx2] = f2bf(W1[k * HIDDEN + n]);
    }
  }
}

// ---------------------------------------------------------------------------
// Fused MLP layer GEMM. Tile: 64 (M) x 512 (N full), 8 waves, BK=32.
// A_F32: A operand is f32 (feat), else bf16 (h). FUSE: apply W2 [512,3] + b2,
// emit pred f32 instead of writing h2.
// ---------------------------------------------------------------------------
template<int K, bool A_F32, bool FUSE>
__global__ __launch_bounds__(512) void mlp_gemm(
    const void* __restrict__ Aptr, const unsigned short* __restrict__ WT,
    const float* __restrict__ bias, const float* __restrict__ W2,
    const float* __restrict__ b2, unsigned short* __restrict__ Hout,
    float* __restrict__ Pout) {
  constexpr int BK = 32;
  constexpr int LDP = 40;  // padded LDS row stride (bf16 elems): 80B -> 2-way banks only
  __shared__ __align__(16) unsigned short Alds[64 * LDP];
  __shared__ __align__(16) unsigned short Blds[HIDDEN * LDP];
  __shared__ float Ppart[8][64 * 3];

  const int tid = threadIdx.x;
  const int w = tid >> 6;
  const int l = tid & 63;
  const int lhi = l >> 4, llo = l & 15;
  const int m0 = blockIdx.x * 64;

  f32x4 acc[4][4];
#pragma unroll
  for (int mt = 0; mt < 4; ++mt)
#pragma unroll
    for (int nt = 0; nt < 4; ++nt) acc[mt][nt] = 0.0f;

  for (int k0 = 0; k0 < K; k0 += BK) {
    // ---- stage A tile (64 x 32) ----
    if constexpr (A_F32) {
      int row = tid >> 3, ch = tid & 7;
      const float4v av = *(const float4v*)((const float*)Aptr + (size_t)(m0 + row) * K + k0 + ch * 4);
      uint2v pk;
      pk.x = (unsigned int)f2bf(av[0]) | ((unsigned int)f2bf(av[1]) << 16);
      pk.y = (unsigned int)f2bf(av[2]) | ((unsigned int)f2bf(av[3]) << 16);
      *(uint2v*)&Alds[row * LDP + ch * 4] = pk;
    } else {
      if (tid < 256) {
        int row = tid >> 2, ch = tid & 3;
        int4v av = *(const int4v*)((const unsigned short*)Aptr + (size_t)(m0 + row) * K + k0 + ch * 8);
        *(int4v*)&Alds[row * LDP + ch * 8] = av;
      }
    }
    // ---- stage B tile (512 n x 32 k), from transposed weights ----
    {
      const unsigned short* src = WT + (size_t)tid * K + k0;
#pragma unroll
      for (int j = 0; j < 4; ++j) {
        int4v bv = *(const int4v*)(src + j * 8);
        *(int4v*)&Blds[tid * LDP + j * 8] = bv;
      }
    }
    __syncthreads();

    short8 a[4], b[4];
#pragma unroll
    for (int mt = 0; mt < 4; ++mt)
      a[mt] = *(const short8*)&Alds[(mt * 16 + llo) * LDP + lhi * 8];
#pragma unroll
    for (int nt = 0; nt < 4; ++nt)
      b[nt] = *(const short8*)&Blds[(w * 64 + nt * 16 + llo) * LDP + lhi * 8];
#pragma unroll
    for (int mt = 0; mt < 4; ++mt)
#pragma unroll
      for (int nt = 0; nt < 4; ++nt)
        acc[mt][nt] = __builtin_amdgcn_mfma_f32_16x16x32_bf16(a[mt], b[nt], acc[mt][nt], 0, 0, 0);
    __syncthreads();
  }

  if constexpr (!FUSE) {
    // h = silu(acc + b0), bf16 store
#pragma unroll
    for (int nt = 0; nt < 4; ++nt) {
      int n = w * 64 + nt * 16 + llo;
      float bn = bias[n];
#pragma unroll
      for (int mt = 0; mt < 4; ++mt) {
        int mbase = m0 + mt * 16 + lhi * 4;
#pragma unroll
        for (int r = 0; r < 4; ++r) {
          float v = silu_f(acc[mt][nt][r] + bn);
          Hout[(size_t)(mbase + r) * HIDDEN + n] = f2bf(v);
        }
      }
    }
  } else {
    // pred = silu(acc + b1) @ W2 + b2
#pragma unroll
    for (int mt = 0; mt < 4; ++mt) {
      float pr[4][3];
#pragma unroll
      for (int r = 0; r < 4; ++r) { pr[r][0] = 0.f; pr[r][1] = 0.f; pr[r][2] = 0.f; }
#pragma unroll
      for (int nt = 0; nt < 4; ++nt) {
        int n = w * 64 + nt * 16 + llo;
        float bn = bias[n];
        float w20 = W2[n * 3 + 0], w21 = W2[n * 3 + 1], w22 = W2[n * 3 + 2];
#pragma unroll
        for (int r = 0; r < 4; ++r) {
          float s = silu_f(acc[mt][nt][r] + bn);
          pr[r][0] += s * w20; pr[r][1] += s * w21; pr[r][2] += s * w22;
        }
      }
#pragma unroll
      for (int r = 0; r < 4; ++r)
#pragma unroll
        for (int o = 0; o < 3; ++o) {
          float v = pr[r][o];
          v += __shfl_xor(v, 1);
          v += __shfl_xor(v, 2);
          v += __shfl_xor(v, 4);
          v += __shfl_xor(v, 8);
          if (llo == 0) Ppart[w][(mt * 16 + lhi * 4 + r) * 3 + o] = v;
        }
    }
    __syncthreads();
    if (tid < 192) {
      float v = b2[tid % 3];
#pragma unroll
      for (int ww = 0; ww < 8; ++ww) v += Ppart[ww][tid];
      Pout[(size_t)m0 * 3 + tid] = v;
    }
  }
}

// ---------------------------------------------------------------------------
// Per-graph finalize: mean removal + analytic torque removal.
// One block per graph (256 nodes).
// ---------------------------------------------------------------------------
template<int NV>
__device__ __forceinline__ void block_reduce(const float* v, float (*sc)[16], int wid, int lane,
                                             float* tot) {
#pragma unroll
  for (int j = 0; j < NV; ++j) {
    float x = v[j];
#pragma unroll
    for (int off = 32; off >= 1; off >>= 1) x += __shfl_down(x, off);
    if (lane == 0) sc[wid][j] = x;
  }
  __syncthreads();
#pragma unroll
  for (int j = 0; j < NV; ++j) tot[j] = sc[0][j] + sc[1][j] + sc[2][j] + sc[3][j];
  __syncthreads();
}

__global__ __launch_bounds__(256) void finalize_kernel(
    const float* __restrict__ pred, const float* __restrict__ pos,
    const float* __restrict__ cell, const int* __restrict__ n_node,
    float* __restrict__ out) {
  __shared__ float sc[4][16];
  int g = blockIdx.x, tid = threadIdx.x;
  int wid = tid >> 6, lane = tid & 63;
  size_t i = (size_t)g * NPG + tid;

  float p0 = pred[i * 3 + 0], p1 = pred[i * 3 + 1], p2 = pred[i * 3 + 2];
  float q0 = pos[i * 3 + 0], q1 = pos[i * 3 + 1], q2 = pos[i * 3 + 2];

  float v1[6] = {p0, p1, p2, q0, q1, q2};
  float t1[6];
  block_reduce<6>(v1, sc, wid, lane, t1);

  float cnt = (float)n_node[g];
  float pc0 = p0 - t1[0] / cnt, pc1 = p1 - t1[1] / cnt, pc2 = p2 - t1[2] / cnt;
  float r0 = q0 - t1[3] / cnt, r1 = q1 - t1[4] / cnt, r2 = q2 - t1[5] / cnt;

  float v2[10] = {r1 * pc2 - r2 * pc1, r2 * pc0 - r0 * pc2, r0 * pc1 - r1 * pc0,
                  r0 * r0 + r1 * r1 + r2 * r2,
                  r0 * r0, r0 * r1, r0 * r2, r1 * r1, r1 * r2, r2 * r2};
  float t2[10];
  block_reduce<10>(v2, sc, wid, lane, t2);

  double s = (double)t2[3];
  double a = (double)t2[4] - s, b = (double)t2[5], c = (double)t2[6];
  double d = (double)t2[7] - s, e = (double)t2[8], f = (double)t2[9] - s;
  double A00 = d * f - e * e;
  double A01 = c * e - b * f;
  double A02 = b * e - c * d;
  double A11 = a * f - c * c;
  double A12 = b * c - a * e;
  double A22 = a * d - b * b;
  double det = a * A00 + b * A01 + c * A02;
  double rinv = 1.0 / det;
  double rhs0 = -(double)t2[0], rhs1 = -(double)t2[1], rhs2 = -(double)t2[2];
  double mu0 = (A00 * rhs0 + A01 * rhs1 + A02 * rhs2) * rinv;
  double mu1 = (A01 * rhs0 + A11 * rhs1 + A12 * rhs2) * rinv;
  double mu2 = (A02 * rhs0 + A12 * rhs1 + A22 * rhs2) * rinv;

  bool nopbc = true;
#pragma unroll
  for (int j = 0; j < 9; ++j) nopbc = nopbc && (cell[g * 9 + j] == 0.0f);

  float d0 = (float)((double)r1 * mu2 - (double)r2 * mu1);
  float d1 = (float)((double)r2 * mu0 - (double)r0 * mu2);
  float d2 = (float)((double)r0 * mu1 - (double)r1 * mu0);

  out[i * 3 + 0] = pc0 + (nopbc ? d0 : 0.0f);
  out[i * 3 + 1] = pc1 + (nopbc ? d1 : 0.0f);
  out[i * 3 + 2] = pc2 + (nopbc ? d2 : 0.0f);
}

// ---------------------------------------------------------------------------
extern "C" void kernel_launch(void* const* d_in, const int* in_sizes, int n_in,
                              void* d_out, int out_size, void* d_ws, size_t ws_size,
                              hipStream_t stream) {
  const float* feat = (const float*)d_in[0];
  const float* positions = (const float*)d_in[1];
  const float* cell = (const float*)d_in[2];
  const int* n_node = (const int*)d_in[3];
  const float* W0 = (const float*)d_in[4];
  const float* b0 = (const float*)d_in[5];
  const float* W1 = (const float*)d_in[6];
  const float* b1 = (const float*)d_in[7];
  const float* W2 = (const float*)d_in[8];
  const float* b2 = (const float*)d_in[9];
  float* out = (float*)d_out;

  char* ws = (char*)d_ws;
  unsigned short* H = (unsigned short*)ws;                    // 262144*512*2 = 256 MiB
  size_t off = (size_t)N_NODES * HIDDEN * 2;
  unsigned short* W0T = (unsigned short*)(ws + off);
  off += (size_t)HIDDEN * LATENT * 2;
  unsigned short* W1T = (unsigned short*)(ws + off);
  off += (size_t)HIDDEN * HIDDEN * 2;
  float* pred = (float*)(ws + off);

  hipLaunchKernelGGL(prep_weights, dim3((HIDDEN * LATENT + HIDDEN * HIDDEN) / 256), dim3(256), 0,
                     stream, W0, W1, W0T, W1T);
  hipLaunchKernelGGL((mlp_gemm<LATENT, true, false>), dim3(N_NODES / 64), dim3(512), 0, stream,
                     (const void*)feat, W0T, b0, nullptr, nullptr, H, nullptr);
  hipLaunchKernelGGL((mlp_gemm<HIDDEN, false, true>), dim3(N_NODES / 64), dim3(512), 0, stream,
                     (const void*)H, W1T, b1, W2, b2, nullptr, pred);
  hipLaunchKernelGGL(finalize_kernel, dim3(BGRAPHS), dim3(256), 0, stream, pred, positions, cell,
                     n_node, out);
}

// Round 2
// 412.244 us; speedup vs baseline: 1.7840x; 1.7840x over previous
//
#include <hip/hip_runtime.h>

#define N_NODES 262144
#define BGRAPHS 1024
#define NPG 256
#define LATENT 256
#define HIDDEN 512

typedef unsigned short ushort_t;
typedef __attribute__((ext_vector_type(4))) float  f32x4;
typedef __attribute__((ext_vector_type(8))) short  short8;
typedef __attribute__((ext_vector_type(4))) int    int4v;
typedef __attribute__((ext_vector_type(2))) unsigned int uint2v;
typedef __attribute__((ext_vector_type(4))) float  float4v;

#define GLOBAL_AS __attribute__((address_space(1)))
#define LDS_AS __attribute__((address_space(3)))

__device__ __forceinline__ unsigned int f2bf(float f) {
  union { float f; unsigned int u; } v; v.f = f;
  unsigned int u = v.u;
  return (u + 0x7fffu + ((u >> 16) & 1u)) >> 16;
}
__device__ __forceinline__ float silu_f(float x) { return x / (1.0f + __expf(-x)); }

// ---------------------------------------------------------------------------
// Weight prep: pre-tile W0/W1 (f32, k-major [K][N]) into the exact LDS staging
// image: per K-step (BK=32) a contiguous 32 KB block laid out
// [slot 0..3][n 0..511][8 bf16], slot = k-octet within the step.
// cell c (16 B): kstep=c>>11, slot=(c>>9)&3, n=c&511, k=kstep*32+slot*8+j.
// ---------------------------------------------------------------------------
__global__ void prep_weights(const float* __restrict__ W0, const float* __restrict__ W1,
                             ushort_t* __restrict__ W0pre, ushort_t* __restrict__ W1pre) {
  int c = blockIdx.x * 256 + threadIdx.x;
  const int C0 = (HIDDEN * LATENT) / 8;   // 16384 cells
  const float* src;
  ushort_t* dst;
  int cc;
  if (c < C0) { src = W0; dst = W0pre; cc = c; }
  else        { src = W1; dst = W1pre; cc = c - C0; }
  int kstep = cc >> 11;
  int slot = (cc >> 9) & 3;
  int n = cc & 511;
  int kb = kstep * 32 + slot * 8;
  unsigned int w[4];
#pragma unroll
  for (int j = 0; j < 4; ++j) {
    unsigned lo = f2bf(src[(size_t)(kb + 2 * j) * HIDDEN + n]);
    unsigned hi = f2bf(src[(size_t)(kb + 2 * j + 1) * HIDDEN + n]);
    w[j] = lo | (hi << 16);
  }
  *(int4v*)(dst + (size_t)cc * 8) = *(int4v*)w;
}

// ---------------------------------------------------------------------------
// Fused MLP: per block M=64 rows, full N. h1 stays in LDS; weights streamed
// via global_load_lds double-buffer from the pre-tiled image.
// ---------------------------------------------------------------------------
__device__ __forceinline__ void stage_w(const ushort_t* src_step, char* dstbuf, int wid, int lane) {
#pragma unroll
  for (int p = 0; p < 4; ++p) {
    const char* g = (const char*)src_step + p * 8192 + wid * 1024 + lane * 16;
    char* l = dstbuf + p * 8192 + wid * 1024;
    __builtin_amdgcn_global_load_lds((const GLOBAL_AS void*)g, (LDS_AS void*)l, 16, 0, 0);
  }
}

__device__ __forceinline__ float4v load_a(const float* feat, int m0, int k0, int tid) {
  int slot = tid >> 7, m = (tid >> 1) & 63, half = tid & 1;
  return *(const float4v*)(feat + (size_t)(m0 + m) * LATENT + k0 + slot * 8 + half * 4);
}
__device__ __forceinline__ void store_a(char* Ad, float4v v, int tid) {
  int slot = tid >> 7, m = (tid >> 1) & 63, half = tid & 1;
  uint2v pk;
  pk.x = f2bf(v[0]) | (f2bf(v[1]) << 16);
  pk.y = f2bf(v[2]) | (f2bf(v[3]) << 16);
  *(uint2v*)(Ad + slot * 1024 + m * 16 + half * 8) = pk;
}

__global__ __launch_bounds__(512) void fused_mlp(
    const float* __restrict__ feat, const ushort_t* __restrict__ W0pre,
    const ushort_t* __restrict__ W1pre, const float* __restrict__ b0,
    const float* __restrict__ b1, const float* __restrict__ W2,
    const float* __restrict__ b2, float* __restrict__ pred) {
  __shared__ __align__(16) char smem[155664];
  char* Wb0 = smem;                 // 32 KB weight staging buf 0
  char* Wb1 = smem + 32768;         // 32 KB weight staging buf 1
  char* Hc  = smem + 65536;         // 64 KB h1 [m 0..63][n 0..511] bf16, XOR-swizzled rows
  char* Adc = smem + 131072;        // 2 x 4 KB feat tile double buffer [slot][m][16B]
  float* b0l = (float*)(smem + 139264);
  float* b1l = (float*)(smem + 141312);
  float* W2l = (float*)(smem + 143360);
  float* b2l = (float*)(smem + 149504);
  float* Pp  = (float*)(smem + 149520);  // 8*64*3 f32 partials

  const int tid = threadIdx.x;
  const int wid = tid >> 6;
  const int lane = tid & 63;
  const int llo = lane & 15;
  const int lhi = lane >> 4;
  const int m0 = blockIdx.x * 64;

  // ---- prologue: bias/W2 staging + first A tile + first W step ----
  b0l[tid] = b0[tid];
  b1l[tid] = b1[tid];
#pragma unroll
  for (int i = 0; i < 3; ++i) W2l[tid + i * 512] = W2[tid + i * 512];
  if (tid == 0) { b2l[0] = b2[0]; b2l[1] = b2[1]; b2l[2] = b2[2]; }
  store_a(Adc, load_a(feat, m0, 0, tid), tid);
  stage_w(W0pre, Wb0, wid, lane);
  __syncthreads();

  f32x4 acc[4][4];
#pragma unroll
  for (int nt = 0; nt < 4; ++nt)
#pragma unroll
    for (int mt = 0; mt < 4; ++mt) acc[nt][mt] = 0.0f;

  // ================= GEMM1: h1' = W0^T x feat^T (8 K-steps) =================
  for (int t = 0; t < 8; ++t) {
    float4v areg = {};
    if (t < 7) areg = load_a(feat, m0, (t + 1) * 32, tid);
    stage_w(t < 7 ? W0pre + (t + 1) * 16384 : W1pre, (t & 1) ? Wb0 : Wb1, wid, lane);

    const char* WbC = (t & 1) ? Wb1 : Wb0;
    const char* AdT = Adc + (t & 1) * 4096;
    short8 wf[4], xf[4];
#pragma unroll
    for (int nt = 0; nt < 4; ++nt)
      wf[nt] = *(const short8*)(WbC + lhi * 8192 + (wid * 64 + nt * 16 + llo) * 16);
#pragma unroll
    for (int mt = 0; mt < 4; ++mt)
      xf[mt] = *(const short8*)(AdT + lhi * 1024 + (mt * 16 + llo) * 16);
#pragma unroll
    for (int nt = 0; nt < 4; ++nt)
#pragma unroll
      for (int mt = 0; mt < 4; ++mt)
        acc[nt][mt] = __builtin_amdgcn_mfma_f32_16x16x32_bf16(wf[nt], xf[mt], acc[nt][mt], 0, 0, 0);

    if (t < 7) store_a(Adc + ((t + 1) & 1) * 4096, areg, tid);
    __syncthreads();
  }

  // ---- epilogue 1: h1 = silu(acc + b0) -> LDS H (swizzled) ----
#pragma unroll
  for (int nt = 0; nt < 4; ++nt) {
    int nb = wid * 64 + nt * 16 + lhi * 4;
    f32x4 bv = *(const f32x4*)(b0l + nb);
#pragma unroll
    for (int mt = 0; mt < 4; ++mt) {
      int m = mt * 16 + llo;
      uint2v pk;
      pk.x = f2bf(silu_f(acc[nt][mt][0] + bv[0])) | (f2bf(silu_f(acc[nt][mt][1] + bv[1])) << 16);
      pk.y = f2bf(silu_f(acc[nt][mt][2] + bv[2])) | (f2bf(silu_f(acc[nt][mt][3] + bv[3])) << 16);
      *(uint2v*)(Hc + m * 1024 + ((nb * 2) ^ ((m & 7) << 4))) = pk;
    }
  }
  __syncthreads();

  // ================= GEMM2: h2' = W1^T x h1^T (16 K-steps) =================
#pragma unroll
  for (int nt = 0; nt < 4; ++nt)
#pragma unroll
    for (int mt = 0; mt < 4; ++mt) acc[nt][mt] = 0.0f;

  for (int t = 0; t < 16; ++t) {
    if (t < 15) stage_w(W1pre + (t + 1) * 16384, (t & 1) ? Wb0 : Wb1, wid, lane);

    const char* WbC = (t & 1) ? Wb1 : Wb0;
    short8 wf[4], xf[4];
#pragma unroll
    for (int nt = 0; nt < 4; ++nt)
      wf[nt] = *(const short8*)(WbC + lhi * 8192 + (wid * 64 + nt * 16 + llo) * 16);
#pragma unroll
    for (int mt = 0; mt < 4; ++mt) {
      int m = mt * 16 + llo;
      xf[mt] = *(const short8*)(Hc + m * 1024 + (((t * 64) + lhi * 16) ^ ((m & 7) << 4)));
    }
#pragma unroll
    for (int nt = 0; nt < 4; ++nt)
#pragma unroll
      for (int mt = 0; mt < 4; ++mt)
        acc[nt][mt] = __builtin_amdgcn_mfma_f32_16x16x32_bf16(wf[nt], xf[mt], acc[nt][mt], 0, 0, 0);
    __syncthreads();
  }

  // ---- epilogue 2: pred = silu(acc + b1) @ W2 + b2 ----
  float p[4][3];
#pragma unroll
  for (int mt = 0; mt < 4; ++mt) { p[mt][0] = 0.f; p[mt][1] = 0.f; p[mt][2] = 0.f; }
#pragma unroll
  for (int nt = 0; nt < 4; ++nt) {
    int nb = wid * 64 + nt * 16 + lhi * 4;
    f32x4 bv = *(const f32x4*)(b1l + nb);
#pragma unroll
    for (int r = 0; r < 4; ++r) {
      float w20 = W2l[(nb + r) * 3 + 0];
      float w21 = W2l[(nb + r) * 3 + 1];
      float w22 = W2l[(nb + r) * 3 + 2];
#pragma unroll
      for (int mt = 0; mt < 4; ++mt) {
        float h = silu_f(acc[nt][mt][r] + bv[r]);
        p[mt][0] += h * w20; p[mt][1] += h * w21; p[mt][2] += h * w22;
      }
    }
  }
#pragma unroll
  for (int mt = 0; mt < 4; ++mt)
#pragma unroll
    for (int o = 0; o < 3; ++o) {
      float v = p[mt][o];
      v += __shfl_xor(v, 16);
      v += __shfl_xor(v, 32);
      p[mt][o] = v;
    }
  if (lane < 16) {
#pragma unroll
    for (int mt = 0; mt < 4; ++mt)
#pragma unroll
      for (int o = 0; o < 3; ++o) Pp[wid * 192 + (mt * 16 + llo) * 3 + o] = p[mt][o];
  }
  __syncthreads();
  if (tid < 192) {
    float v = b2l[tid % 3];
#pragma unroll
    for (int ww = 0; ww < 8; ++ww) v += Pp[ww * 192 + tid];
    pred[(size_t)m0 * 3 + tid] = v;
  }
}

// ---------------------------------------------------------------------------
// Per-graph finalize: mean removal + analytic torque removal. 1 block/graph.
// ---------------------------------------------------------------------------
template<int NV>
__device__ __forceinline__ void block_reduce(const float* v, float (*sc)[16], int wid, int lane,
                                             float* tot) {
#pragma unroll
  for (int j = 0; j < NV; ++j) {
    float x = v[j];
#pragma unroll
    for (int off = 32; off >= 1; off >>= 1) x += __shfl_down(x, off);
    if (lane == 0) sc[wid][j] = x;
  }
  __syncthreads();
#pragma unroll
  for (int j = 0; j < NV; ++j) tot[j] = sc[0][j] + sc[1][j] + sc[2][j] + sc[3][j];
  __syncthreads();
}

__global__ __launch_bounds__(256) void finalize_kernel(
    const float* __restrict__ pred, const float* __restrict__ pos,
    const float* __restrict__ cell, const int* __restrict__ n_node,
    float* __restrict__ out) {
  __shared__ float sc[4][16];
  int g = blockIdx.x, tid = threadIdx.x;
  int wid = tid >> 6, lane = tid & 63;
  size_t i = (size_t)g * NPG + tid;

  float p0 = pred[i * 3 + 0], p1 = pred[i * 3 + 1], p2 = pred[i * 3 + 2];
  float q0 = pos[i * 3 + 0], q1 = pos[i * 3 + 1], q2 = pos[i * 3 + 2];

  float v1[6] = {p0, p1, p2, q0, q1, q2};
  float t1[6];
  block_reduce<6>(v1, sc, wid, lane, t1);

  float cnt = (float)n_node[g];
  float pc0 = p0 - t1[0] / cnt, pc1 = p1 - t1[1] / cnt, pc2 = p2 - t1[2] / cnt;
  float r0 = q0 - t1[3] / cnt, r1 = q1 - t1[4] / cnt, r2 = q2 - t1[5] / cnt;

  float v2[10] = {r1 * pc2 - r2 * pc1, r2 * pc0 - r0 * pc2, r0 * pc1 - r1 * pc0,
                  r0 * r0 + r1 * r1 + r2 * r2,
                  r0 * r0, r0 * r1, r0 * r2, r1 * r1, r1 * r2, r2 * r2};
  float t2[10];
  block_reduce<10>(v2, sc, wid, lane, t2);

  double s = (double)t2[3];
  double a = (double)t2[4] - s, b = (double)t2[5], c = (double)t2[6];
  double d = (double)t2[7] - s, e = (double)t2[8], f = (double)t2[9] - s;
  double A00 = d * f - e * e;
  double A01 = c * e - b * f;
  double A02 = b * e - c * d;
  double A11 = a * f - c * c;
  double A12 = b * c - a * e;
  double A22 = a * d - b * b;
  double det = a * A00 + b * A01 + c * A02;
  double rinv = 1.0 / det;
  double rhs0 = -(double)t2[0], rhs1 = -(double)t2[1], rhs2 = -(double)t2[2];
  double mu0 = (A00 * rhs0 + A01 * rhs1 + A02 * rhs2) * rinv;
  double mu1 = (A01 * rhs0 + A11 * rhs1 + A12 * rhs2) * rinv;
  double mu2 = (A02 * rhs0 + A12 * rhs1 + A22 * rhs2) * rinv;

  bool nopbc = true;
#pragma unroll
  for (int j = 0; j < 9; ++j) nopbc = nopbc && (cell[g * 9 + j] == 0.0f);

  float d0 = (float)((double)r1 * mu2 - (double)r2 * mu1);
  float d1 = (float)((double)r2 * mu0 - (double)r0 * mu2);
  float d2 = (float)((double)r0 * mu1 - (double)r1 * mu0);

  out[i * 3 + 0] = pc0 + (nopbc ? d0 : 0.0f);
  out[i * 3 + 1] = pc1 + (nopbc ? d1 : 0.0f);
  out[i * 3 + 2] = pc2 + (nopbc ? d2 : 0.0f);
}

// ---------------------------------------------------------------------------
extern "C" void kernel_launch(void* const* d_in, const int* in_sizes, int n_in,
                              void* d_out, int out_size, void* d_ws, size_t ws_size,
                              hipStream_t stream) {
  const float* feat = (const float*)d_in[0];
  const float* positions = (const float*)d_in[1];
  const float* cell = (const float*)d_in[2];
  const int* n_node = (const int*)d_in[3];
  const float* W0 = (const float*)d_in[4];
  const float* b0 = (const float*)d_in[5];
  const float* W1 = (const float*)d_in[6];
  const float* b1 = (const float*)d_in[7];
  const float* W2 = (const float*)d_in[8];
  const float* b2 = (const float*)d_in[9];
  float* out = (float*)d_out;

  char* ws = (char*)d_ws;
  ushort_t* W0pre = (ushort_t*)ws;                       // 256 KB
  ushort_t* W1pre = (ushort_t*)(ws + 262144);            // 512 KB
  float* pred = (float*)(ws + 786432);                   // 3 MB

  hipLaunchKernelGGL(prep_weights, dim3(192), dim3(256), 0, stream, W0, W1, W0pre, W1pre);
  hipLaunchKernelGGL(fused_mlp, dim3(N_NODES / 64), dim3(512), 0, stream,
                     feat, W0pre, W1pre, b0, b1, W2, b2, pred);
  hipLaunchKernelGGL(finalize_kernel, dim3(BGRAPHS), dim3(256), 0, stream, pred, positions, cell,
                     n_node, out);
}